// Round 9
// baseline (60.951 us; speedup 1.0000x reference)
//
#include <hip/hip_runtime.h>

// Problem constants (from reference setup_inputs)
#define B_DIM 8
#define F_DIM 16384
#define K_DIM 3
#define M_DIM 64
#define MCH   8                  // m-values per block in feat kernel
#define LOG2E 1.4426950408889634f

// ws float layout (deterministic, fully overwritten every launch):
//   [0, 16384)     : partial raw sums  slot = m*256 + b*32 + fc
//   [16384, 32768) : partial raw sumsq (same indexing)
//   [32768, 33792) : prescaled kernel-point table, 256 float4
// Raw = un-normalized sum of 16 exps (the /16 is folded into BN coeffs).
#define WS_Q 16384
#define WS_W 32768

// ---------------------------------------------------------------------------
// Kernel 0: precompute kernel-point table (256 float4) into ws.
// ||p||^2 == 1 (unit normals): arg_log2 = 25*log2e*dot - 12.5*log2e*(1+||w||^2)
// ---------------------------------------------------------------------------
__global__ void fkc_wtab_kernel(const float* __restrict__ walpha,
                                const float* __restrict__ wbeta,
                                float* __restrict__ ws)
{
    const int t = threadIdx.x;               // 256 = M*4
    float a = walpha[t], b = wbeta[t];
    float sa = sinf(a), ca = cosf(a);
    float sb = sinf(b), cb = cosf(b);
    float wx = sa * cb, wy = sa * sb, wz = ca;
    float w2 = wx * wx + wy * wy + wz * wz;
    ((float4*)(ws + WS_W))[t] =
        make_float4(wx * 25.0f * LOG2E, wy * 25.0f * LOG2E,
                    wz * 25.0f * LOG2E, -12.5f * LOG2E * (w2 + 1.0f));
}

// ---------------------------------------------------------------------------
// Kernel 1: raw feat sums -> d_out, per-(m,b,fc) partials -> ws.
// grid = 2048 (b8 x mc8 x fc32), block = 256, 2 consecutive f per thread.
// w-table comes from global memory via WAVE-UNIFORM addresses (static after
// full unroll) -> scalar s_load_dwordx4, w components are SGPR operands of
// v_fma. No LDS table, no per-block sin/cos, no initial __syncthreads.
// __launch_bounds__(256,8): cap VGPR at 64 -> 8 waves/SIMD (R8 lost to
// occupancy 26%; R7's winner ran ~48%).
// ---------------------------------------------------------------------------
__global__ __launch_bounds__(256, 8) void fkc_feat_kernel(
    const float*  __restrict__ normals,   // [B,3,F]
    const int*    __restrict__ nidx,      // [B,F,K] int32
    const float4* __restrict__ wtab,      // 256 prescaled kernel points
    float* __restrict__ feat_out,         // [B,M,F] raw sums
    float* __restrict__ ws)
{
    __shared__ float sRS[MCH][32];        // [m][wave*8 + class]
    __shared__ float sRQ[MCH][32];

    const int tid = threadIdx.x;
    const int b  = blockIdx.x >> 8;          // 256 blocks per batch
    const int mc = (blockIdx.x >> 5) & 7;    // m-chunk (8 m each)
    const int fc = blockIdx.x & 31;          // f-chunk (512 f)

    const int f0 = (fc << 9) + tid * 2;      // two consecutive f per thread
    const float* nb = normals + (size_t)b * 3 * F_DIM;

    float pxA[4], pyA[4], pzA[4], pxB[4], pyB[4], pzB[4];
    {
        float2 vx = *(const float2*)(nb + f0);
        float2 vy = *(const float2*)(nb + F_DIM + f0);
        float2 vz = *(const float2*)(nb + 2 * F_DIM + f0);
        pxA[0] = vx.x; pxB[0] = vx.y;
        pyA[0] = vy.x; pyB[0] = vy.y;
        pzA[0] = vz.x; pzB[0] = vz.y;
    }
    {
        const int* ib = nidx + ((size_t)b * F_DIM + f0) * K_DIM;
#pragma unroll
        for (int k = 0; k < K_DIM; ++k) {
            int id = ib[k];
            pxA[k + 1] = nb[id]; pyA[k + 1] = nb[F_DIM + id]; pzA[k + 1] = nb[2 * F_DIM + id];
            id = ib[k + 3];
            pxB[k + 1] = nb[id]; pyB[k + 1] = nb[F_DIM + id]; pzB[k + 1] = nb[2 * F_DIM + id];
        }
    }

    const int wave = tid >> 6, lane = tid & 63;
    const float4* wt = wtab + mc * (MCH * 4);     // this block's 32 entries
    float* outb = feat_out + ((size_t)b * M_DIM + mc * MCH) * F_DIM + f0;

#pragma unroll
    for (int m = 0; m < MCH; ++m) {
        float a0 = 0.f, a1 = 0.f, a2 = 0.f, a3 = 0.f;
        float b0 = 0.f, b1 = 0.f, b2 = 0.f, b3 = 0.f;
#pragma unroll
        for (int j = 0; j < 4; ++j) {
            float4 w = wt[m * 4 + j];        // uniform addr -> s_load, SGPRs
            a0 += __builtin_amdgcn_exp2f(fmaf(w.x, pxA[0], fmaf(w.y, pyA[0], fmaf(w.z, pzA[0], w.w))));
            a1 += __builtin_amdgcn_exp2f(fmaf(w.x, pxA[1], fmaf(w.y, pyA[1], fmaf(w.z, pzA[1], w.w))));
            a2 += __builtin_amdgcn_exp2f(fmaf(w.x, pxA[2], fmaf(w.y, pyA[2], fmaf(w.z, pzA[2], w.w))));
            a3 += __builtin_amdgcn_exp2f(fmaf(w.x, pxA[3], fmaf(w.y, pyA[3], fmaf(w.z, pzA[3], w.w))));
            b0 += __builtin_amdgcn_exp2f(fmaf(w.x, pxB[0], fmaf(w.y, pyB[0], fmaf(w.z, pzB[0], w.w))));
            b1 += __builtin_amdgcn_exp2f(fmaf(w.x, pxB[1], fmaf(w.y, pyB[1], fmaf(w.z, pzB[1], w.w))));
            b2 += __builtin_amdgcn_exp2f(fmaf(w.x, pxB[2], fmaf(w.y, pyB[2], fmaf(w.z, pzB[2], w.w))));
            b3 += __builtin_amdgcn_exp2f(fmaf(w.x, pxB[3], fmaf(w.y, pyB[3], fmaf(w.z, pzB[3], w.w))));
        }
        float SA = (a0 + a1) + (a2 + a3);    // raw sums (no /16)
        float SB = (b0 + b1) + (b2 + b3);
        *(float2*)(outb + (size_t)m * F_DIM) = make_float2(SA, SB);

        // 3-step butterfly (offs 8/16/32): lanes 0-7 hold 8 class sums.
        float s = SA + SB;
        float q = SA * SA + SB * SB;
        s += __shfl_xor(s, 8, 64);  q += __shfl_xor(q, 8, 64);
        s += __shfl_xor(s, 16, 64); q += __shfl_xor(q, 16, 64);
        s += __shfl_xor(s, 32, 64); q += __shfl_xor(q, 32, 64);
        if (lane < 8) { sRS[m][wave * 8 + lane] = s; sRQ[m][wave * 8 + lane] = q; }
    }
    __syncthreads();

    // Fold 32 class-sums per m: thread t<128 -> (m = t>>4, j = t&15).
    if (tid < MCH * 16) {
        const int m = tid >> 4, j = tid & 15;
        float s = sRS[m][j] + sRS[m][j + 16];
        float q = sRQ[m][j] + sRQ[m][j + 16];
        s += __shfl_xor(s, 1, 64);  q += __shfl_xor(q, 1, 64);
        s += __shfl_xor(s, 2, 64);  q += __shfl_xor(q, 2, 64);
        s += __shfl_xor(s, 4, 64);  q += __shfl_xor(q, 4, 64);
        s += __shfl_xor(s, 8, 64);  q += __shfl_xor(q, 8, 64);
        if (j == 0) {
            int slot = (mc * MCH + m) * 256 + b * 32 + fc;
            ws[slot] = s;
            ws[WS_Q + slot] = q;
        }
    }
}

// ---------------------------------------------------------------------------
// Kernel 2: stats + BN + ReLU. grid = B*M = 512 blocks, one (b,m) row each.
// out rows hold RAW sums S; BN coeffs absorb the /16:
//   feat = S/16 ; mean_f = meanS/16 ; E[f^2] = E[S^2]/256
//   out = relu((A/16)*S + (beta - mean_f*A)),  A = gamma*rsqrt(var+eps)
// ---------------------------------------------------------------------------
__global__ __launch_bounds__(256) void fkc_bn_kernel(
    float* __restrict__ out,             // [B,M,F]
    const float* __restrict__ gamma,
    const float* __restrict__ beta,
    const float* __restrict__ ws)
{
    __shared__ float sS[4], sQ[4];
    __shared__ float sAC[2];
    const int row = blockIdx.x;              // b*64 + m
    const int m = row & 63;
    const int tid = threadIdx.x;
    const int wave = tid >> 6, lane = tid & 63;

    // Phase A: reduce 256 partials (one per thread).
    {
        float s = ws[m * 256 + tid];
        float q = ws[WS_Q + m * 256 + tid];
#pragma unroll
        for (int off = 32; off >= 1; off >>= 1) {
            s += __shfl_xor(s, off, 64);
            q += __shfl_xor(q, off, 64);
        }
        if (lane == 0) { sS[wave] = s; sQ[wave] = q; }
    }
    __syncthreads();
    if (tid == 0) {
        float s = (sS[0] + sS[1]) + (sS[2] + sS[3]);
        float q = (sQ[0] + sQ[1]) + (sQ[2] + sQ[3]);
        const float invcnt = 1.0f / (float)(B_DIM * F_DIM);
        float meanS = s * invcnt;
        float meanF = meanS * (1.0f / 16.0f);
        float ef2   = q * invcnt * (1.0f / 256.0f);
        float var   = ef2 - meanF * meanF;
        float inv   = rsqrtf(var + 1e-5f);
        float A = gamma[m] * inv;
        sAC[0] = A * (1.0f / 16.0f);          // applied to raw S
        sAC[1] = beta[m] - meanF * A;
    }
    __syncthreads();

    // Phase B: BN + ReLU over this row, float4.
    const float A = sAC[0], C = sAC[1];
    float4* p4 = (float4*)(out + (size_t)row * F_DIM);
#pragma unroll
    for (int i = 0; i < 16; ++i) {           // 4096 float4 / 256 threads
        float4 v = p4[tid + i * 256];
        v.x = fmaxf(fmaf(v.x, A, C), 0.0f);
        v.y = fmaxf(fmaf(v.y, A, C), 0.0f);
        v.z = fmaxf(fmaf(v.z, A, C), 0.0f);
        v.w = fmaxf(fmaf(v.w, A, C), 0.0f);
        p4[tid + i * 256] = v;
    }
}

// ---------------------------------------------------------------------------
extern "C" void kernel_launch(void* const* d_in, const int* in_sizes, int n_in,
                              void* d_out, int out_size, void* d_ws, size_t ws_size,
                              hipStream_t stream)
{
    const float* normals = (const float*)d_in[0];
    const float* walpha  = (const float*)d_in[1];
    const float* wbeta   = (const float*)d_in[2];
    const float* gamma   = (const float*)d_in[3];
    const float* beta    = (const float*)d_in[4];
    const int*   nidx    = (const int*)d_in[5];
    float* out = (float*)d_out;
    float* ws  = (float*)d_ws;

    // 3 dispatches. No memset, no atomics: every ws slot used is
    // overwritten every launch (poison-safe).
    hipLaunchKernelGGL(fkc_wtab_kernel, dim3(1), dim3(256), 0, stream,
                       walpha, wbeta, ws);
    hipLaunchKernelGGL(fkc_feat_kernel, dim3(2048), dim3(256), 0, stream,
                       normals, nidx, (const float4*)(ws + WS_W), out, ws);
    hipLaunchKernelGGL(fkc_bn_kernel, dim3(B_DIM * M_DIM), dim3(256), 0, stream,
                       out, gamma, beta, ws);
}

// Round 10
// 54.928 us; speedup vs baseline: 1.1096x; 1.1096x over previous
//
#include <hip/hip_runtime.h>

// Problem constants (from reference setup_inputs)
#define B_DIM 8
#define F_DIM 16384
#define K_DIM 3
#define M_DIM 64
#define MCH   16                 // m-values per block in feat kernel
#define LOG2E 1.4426950408889634f

// ws float layout (deterministic, fully overwritten every launch):
//   [0, 32768)     : partial raw sums  slot = m*512 + b*64 + fc
//   [32768, 65536) : partial raw sumsq (same indexing)
//   [65536, 66560) : prescaled kernel-point table, 256 float4
// Raw = un-normalized sum of 16 exps (the /16 is folded into BN coeffs).
#define WS_Q 32768
#define WS_W 65536

// ---------------------------------------------------------------------------
// Kernel 0: precompute kernel-point table (256 float4) into ws.
// ||p||^2 == 1 (unit normals): arg_log2 = 25*log2e*dot - 12.5*log2e*(1+||w||^2)
// ---------------------------------------------------------------------------
__global__ void fkc_wtab_kernel(const float* __restrict__ walpha,
                                const float* __restrict__ wbeta,
                                float* __restrict__ ws)
{
    const int t = threadIdx.x;               // 256 = M*4
    float a = walpha[t], b = wbeta[t];
    float sa = sinf(a), ca = cosf(a);
    float sb = sinf(b), cb = cosf(b);
    float wx = sa * cb, wy = sa * sb, wz = ca;
    float w2 = wx * wx + wy * wy + wz * wz;
    ((float4*)(ws + WS_W))[t] =
        make_float4(wx * 25.0f * LOG2E, wy * 25.0f * LOG2E,
                    wz * 25.0f * LOG2E, -12.5f * LOG2E * (w2 + 1.0f));
}

// ---------------------------------------------------------------------------
// Kernel 1: raw feat sums -> d_out, per-(m,b,fc) partials -> ws.
// R7's winning config (grid 2048 = b8 x mc4 x fc64, block 256, 1 f/thread,
// MCH=16, LDS table) minus prologue trig (table precomputed), minus the /16
// muls (folded into BN), minus one butterfly level per m (2-step {16,32} ->
// 16-lane classes; third level moved to the once-per-block epilogue fold).
// ---------------------------------------------------------------------------
__global__ __launch_bounds__(256) void fkc_feat_kernel(
    const float*  __restrict__ normals,   // [B,3,F]
    const int*    __restrict__ nidx,      // [B,F,K] int32
    const float4* __restrict__ wtab,      // 256 prescaled kernel points
    float* __restrict__ feat_out,         // [B,M,F] raw sums
    float* __restrict__ ws)
{
    __shared__ float4 sW[MCH * 4];
    __shared__ float sRS[MCH][64];        // [m][wave*16 + class]
    __shared__ float sRQ[MCH][64];

    const int tid = threadIdx.x;
    const int b  = blockIdx.x >> 8;          // 256 blocks per batch
    const int mc = (blockIdx.x >> 6) & 3;    // m-chunk (16 m each)
    const int fc = blockIdx.x & 63;          // f-chunk (256 f)

    // Copy this block's 64 table entries global -> LDS (no trig).
    if (tid < MCH * 4) sW[tid] = wtab[mc * MCH * 4 + tid];
    __syncthreads();

    const int f = (fc << 8) + tid;           // coalesced f
    const float* nb = normals + (size_t)b * 3 * F_DIM;
    float px[4], py[4], pz[4];
    px[0] = nb[f]; py[0] = nb[F_DIM + f]; pz[0] = nb[2 * F_DIM + f];
    const int* ib = nidx + ((size_t)b * F_DIM + f) * K_DIM;
#pragma unroll
    for (int k = 0; k < K_DIM; ++k) {
        int id = ib[k];
        px[k + 1] = nb[id]; py[k + 1] = nb[F_DIM + id]; pz[k + 1] = nb[2 * F_DIM + id];
    }

    const int wave = tid >> 6, lane = tid & 63;
    float* outb = feat_out + ((size_t)b * M_DIM + mc * MCH) * F_DIM + f;
#pragma unroll 2
    for (int m = 0; m < MCH; ++m) {
        float s0 = 0.f, s1 = 0.f, s2 = 0.f, s3 = 0.f;
#pragma unroll
        for (int j = 0; j < 4; ++j) {
            float4 w = sW[m * 4 + j];
            s0 += __builtin_amdgcn_exp2f(fmaf(w.x, px[0], fmaf(w.y, py[0], fmaf(w.z, pz[0], w.w))));
            s1 += __builtin_amdgcn_exp2f(fmaf(w.x, px[1], fmaf(w.y, py[1], fmaf(w.z, pz[1], w.w))));
            s2 += __builtin_amdgcn_exp2f(fmaf(w.x, px[2], fmaf(w.y, py[2], fmaf(w.z, pz[2], w.w))));
            s3 += __builtin_amdgcn_exp2f(fmaf(w.x, px[3], fmaf(w.y, py[3], fmaf(w.z, pz[3], w.w))));
        }
        float S = (s0 + s1) + (s2 + s3);     // raw sum (no /16)
        outb[(size_t)m * F_DIM] = S;

        // 2-step butterfly ({16,32}): lanes 0-15 hold 16 class sums.
        float s = S, q = S * S;
        s += __shfl_xor(s, 16, 64); q += __shfl_xor(q, 16, 64);
        s += __shfl_xor(s, 32, 64); q += __shfl_xor(q, 32, 64);
        if (lane < 16) { sRS[m][wave * 16 + lane] = s; sRQ[m][wave * 16 + lane] = q; }
    }
    __syncthreads();

    // Epilogue fold: thread t -> (m = t>>4, j = t&15); 4 LDS reads + 4-step
    // shuffle fold over j.
    {
        const int m = tid >> 4, j = tid & 15;
        float s = (sRS[m][j] + sRS[m][j + 16]) + (sRS[m][j + 32] + sRS[m][j + 48]);
        float q = (sRQ[m][j] + sRQ[m][j + 16]) + (sRQ[m][j + 32] + sRQ[m][j + 48]);
        s += __shfl_xor(s, 1, 64);  q += __shfl_xor(q, 1, 64);
        s += __shfl_xor(s, 2, 64);  q += __shfl_xor(q, 2, 64);
        s += __shfl_xor(s, 4, 64);  q += __shfl_xor(q, 4, 64);
        s += __shfl_xor(s, 8, 64);  q += __shfl_xor(q, 8, 64);
        if (j == 0) {
            int slot = (mc * MCH + m) * 512 + b * 64 + fc;
            ws[slot] = s;
            ws[WS_Q + slot] = q;
        }
    }
}

// ---------------------------------------------------------------------------
// Kernel 2: stats + BN + ReLU. grid = B*M = 512 blocks, one (b,m) row each.
// out rows hold RAW sums S; BN coeffs absorb the /16:
//   feat = S/16 ; mean_f = meanS/16 ; E[f^2] = E[S^2]/256
//   out = relu((A/16)*S + (beta - mean_f*A)),  A = gamma*rsqrt(var+eps)
// ---------------------------------------------------------------------------
__global__ __launch_bounds__(256) void fkc_bn_kernel(
    float* __restrict__ out,             // [B,M,F]
    const float* __restrict__ gamma,
    const float* __restrict__ beta,
    const float* __restrict__ ws)
{
    __shared__ float sS[4], sQ[4];
    __shared__ float sAC[2];
    const int row = blockIdx.x;              // b*64 + m
    const int m = row & 63;
    const int tid = threadIdx.x;
    const int wave = tid >> 6, lane = tid & 63;

    // Phase A: reduce this channel's 512 partials (2 per thread, L2-hot).
    {
        float s = ws[m * 512 + tid]        + ws[m * 512 + tid + 256];
        float q = ws[WS_Q + m * 512 + tid] + ws[WS_Q + m * 512 + tid + 256];
#pragma unroll
        for (int off = 32; off >= 1; off >>= 1) {
            s += __shfl_xor(s, off, 64);
            q += __shfl_xor(q, off, 64);
        }
        if (lane == 0) { sS[wave] = s; sQ[wave] = q; }
    }
    __syncthreads();
    if (tid == 0) {
        float s = (sS[0] + sS[1]) + (sS[2] + sS[3]);
        float q = (sQ[0] + sQ[1]) + (sQ[2] + sQ[3]);
        const float invcnt = 1.0f / (float)(B_DIM * F_DIM);
        float meanS = s * invcnt;
        float meanF = meanS * (1.0f / 16.0f);
        float ef2   = q * invcnt * (1.0f / 256.0f);
        float var   = ef2 - meanF * meanF;
        float inv   = rsqrtf(var + 1e-5f);
        float A = gamma[m] * inv;
        sAC[0] = A * (1.0f / 16.0f);          // applied to raw S
        sAC[1] = beta[m] - meanF * A;
    }
    __syncthreads();

    // Phase B: BN + ReLU over this row, float4.
    const float A = sAC[0], C = sAC[1];
    float4* p4 = (float4*)(out + (size_t)row * F_DIM);
#pragma unroll
    for (int i = 0; i < 16; ++i) {           // 4096 float4 / 256 threads
        float4 v = p4[tid + i * 256];
        v.x = fmaxf(fmaf(v.x, A, C), 0.0f);
        v.y = fmaxf(fmaf(v.y, A, C), 0.0f);
        v.z = fmaxf(fmaf(v.z, A, C), 0.0f);
        v.w = fmaxf(fmaf(v.w, A, C), 0.0f);
        p4[tid + i * 256] = v;
    }
}

// ---------------------------------------------------------------------------
extern "C" void kernel_launch(void* const* d_in, const int* in_sizes, int n_in,
                              void* d_out, int out_size, void* d_ws, size_t ws_size,
                              hipStream_t stream)
{
    const float* normals = (const float*)d_in[0];
    const float* walpha  = (const float*)d_in[1];
    const float* wbeta   = (const float*)d_in[2];
    const float* gamma   = (const float*)d_in[3];
    const float* beta    = (const float*)d_in[4];
    const int*   nidx    = (const int*)d_in[5];
    float* out = (float*)d_out;
    float* ws  = (float*)d_ws;

    // 3 dispatches. No memset, no atomics: every ws slot used is
    // overwritten every launch (poison-safe).
    hipLaunchKernelGGL(fkc_wtab_kernel, dim3(1), dim3(256), 0, stream,
                       walpha, wbeta, ws);
    hipLaunchKernelGGL(fkc_feat_kernel, dim3(2048), dim3(256), 0, stream,
                       normals, nidx, (const float4*)(ws + WS_W), out, ws);
    hipLaunchKernelGGL(fkc_bn_kernel, dim3(B_DIM * M_DIM), dim3(256), 0, stream,
                       out, gamma, beta, ws);
}